// Round 5
// baseline (633.108 us; speedup 1.0000x reference)
//
#include <hip/hip_runtime.h>

#define BATCH 32
#define NLEN  1024
#define NUMV  (BATCH * NLEN)

typedef __attribute__((ext_vector_type(8))) short short8;
typedef __attribute__((ext_vector_type(4))) float f32x4;

__device__ inline unsigned short rne_bf16(float x) {
    union { float f; unsigned u; } a; a.f = x;
    return (unsigned short)((a.u + 0x7FFFu + ((a.u >> 16) & 1u)) >> 16);
}
// fp32 -> bf16 hi + bf16 lo (both RNE): x ~= hi + lo, rel err ~2^-17
__device__ inline void bsplit(float x, unsigned short& h, unsigned short& l) {
    union { float f; unsigned u; } a; a.f = x;
    unsigned hb = (a.u + 0x7FFFu + ((a.u >> 16) & 1u)) & 0xFFFF0000u;
    h = (unsigned short)(hb >> 16);
    union { unsigned u; float f; } hf; hf.u = hb;
    l = rne_bf16(x - hf.f);
}
__device__ inline float bf16_to_f(unsigned short v) {
    union { unsigned u; float f; } a; a.u = ((unsigned)v) << 16; return a.f;
}

// Packed layout per layer (bank-conflict-free transposed chunks):
//   f = ((nt*KC + kc)*2 + hl)*512 + g*128 + c*8 + j
//   -> W[k = kc*32+g*8+j][col = nt*16+c], W = [Wm | Ws], zero-pad k >= CIN.
// hl: 0 = hi bf16, 1 = lo bf16. One B tile (all kc, hi+lo) contiguous: KC*2KB.
template<int CIN, int COUT, int H>
__device__ void pack_layer(const float* __restrict__ Wm, const float* __restrict__ Ws,
                           unsigned short* __restrict__ out, int t0, int nthr)
{
    constexpr int HC = H * COUT;
    constexpr int KC = ((CIN + 31) & ~31) / 32;
    constexpr int NT = (HC + COUT) / 16;
    const int total = NT * KC * 1024;
    for (int f = t0; f < total; f += nthr) {
        int j  = f & 7;
        int c  = (f >> 3) & 15;
        int g  = (f >> 7) & 3;
        int hl = (f >> 9) & 1;
        int r2 = f >> 10;
        int kc = r2 % KC, nt = r2 / KC;
        int k = kc * 32 + g * 8 + j, col = nt * 16 + c;
        float v = 0.f;
        if (k < CIN) v = (col < HC) ? Wm[k * HC + col] : Ws[k * COUT + (col - HC)];
        unsigned short h, l; bsplit(v, h, l);
        out[f] = hl ? l : h;
    }
}

__global__ void pack_all(const float* Wm1, const float* Ws1, const float* Wm2, const float* Ws2,
                         const float* Wm3, const float* Ws3, const float* Wm4, const float* Ws4,
                         unsigned short* p1, unsigned short* p2, unsigned short* p3, unsigned short* p4)
{
    int t = blockIdx.x * 256 + threadIdx.x;
    int n = gridDim.x * 256;
    pack_layer<1, 128, 8>(Wm1, Ws1, p1, t, n);
    pack_layer<128, 128, 8>(Wm2, Ws2, p2, t, n);
    pack_layer<128, 64, 16>(Wm3, Ws3, p3, t, n);
    pack_layer<64, 64, 16>(Wm4, Ws4, p4, t, n);
}

// Register-resident fused GeneralConv layer.
// Block = 2 waves; each wave owns ONE 16-row set (14 useful + 2 halo); block = 28 useful rows.
// Grid = 32 graphs * 37 tiles = 1184 blocks (~4.6 blocks/CU -> latency hiding).
// bm/att/bs staged in LDS (no per-tile global loads); B double-buffered in LDS;
// MFMA accumulation split into 3 independent chains (hi*hi / hi*lo / lo*hi).
template<int CIN, int COUT, int H, bool MPACK>
__global__ __launch_bounds__(128, 4)
void conv_reg(const float* __restrict__ x, const unsigned short* __restrict__ pw,
              const float* __restrict__ bm, const float* __restrict__ bs,
              const float* __restrict__ att, float* __restrict__ y)
{
    constexpr int HC = H * COUT;
    static_assert(HC == 1024, "");
    constexpr int KC   = ((CIN + 31) & ~31) / 32;
    constexpr int HT   = COUT / 16;          // tiles per head == self tiles
    constexpr int MT   = HC / 16;            // 64 message tiles
    constexpr int NTOT = MT + HT;
    constexpr int NCH  = KC * 128;           // 16B chunks per B tile
    constexpr int NTHR = 128;
    constexpr int CHPT = (NCH + NTHR - 1) / NTHR;
    constexpr int ROWSB = 28;
    constexpr int TPG  = (NLEN + ROWSB - 1) / ROWSB;  // 37
    constexpr int PL   = HC + COUT;          // param cols
    constexpr float invH = 1.0f / H;

    const int tid  = threadIdx.x;
    const int lane = tid & 63;
    const int w    = tid >> 6;                // wave 0..1
    const int r    = lane & 15;               // A row in set / B col / C col
    const int gg   = lane >> 4;               // k-group; C row = gg*4+e
    const int g    = blockIdx.x / TPG;
    const int n0   = (blockIdx.x % TPG) * ROWSB;
    const size_t gstart = (size_t)g * NLEN;

    __shared__ alignas(16) unsigned short bufs[2][KC * 1024];
    __shared__ alignas(8) float pl[PL * 2];   // (bm,att) pairs for msg cols; (bs,0) for self cols

    // ---- prologue: params -> LDS, B tile 0 -> LDS ----
    for (int i = tid; i < PL; i += NTHR) {
        if (i < HC) { pl[2 * i] = bm[i]; pl[2 * i + 1] = att[i]; }
        else        { pl[2 * i] = bs[i - HC]; pl[2 * i + 1] = 0.f; }
    }
    {
        const f32x4* ps = (const f32x4*)pw;
        f32x4 sreg[CHPT];
        #pragma unroll
        for (int i = 0; i < CHPT; i++) { int idx = tid + i * NTHR; if (idx < NCH) sreg[i] = ps[idx]; }
        #pragma unroll
        for (int i = 0; i < CHPT; i++) { int idx = tid + i * NTHR; if (idx < NCH) *(f32x4*)&bufs[0][idx * 8] = sreg[i]; }
    }

    // ---- A fragments (one row-set, built once from global) ----
    short8 a_hi[KC], a_lo[KC];
    {
        const int na = n0 - 1 + w * 14 + r;          // within-graph node of A row
        const bool av = (na >= 0) && (na < NLEN);
        const float* xrow = x + (gstart + (size_t)(av ? na : 0)) * CIN;
        #pragma unroll
        for (int kc = 0; kc < KC; kc++) {
            float vals[8];
            if constexpr (CIN % 32 == 0) {
                if (av) {
                    f32x4 v0 = *(const f32x4*)(xrow + kc * 32 + gg * 8);
                    f32x4 v1 = *(const f32x4*)(xrow + kc * 32 + gg * 8 + 4);
                    vals[0]=v0[0]; vals[1]=v0[1]; vals[2]=v0[2]; vals[3]=v0[3];
                    vals[4]=v1[0]; vals[5]=v1[1]; vals[6]=v1[2]; vals[7]=v1[3];
                } else {
                    #pragma unroll
                    for (int jj = 0; jj < 8; jj++) vals[jj] = 0.f;
                }
            } else {
                #pragma unroll
                for (int jj = 0; jj < 8; jj++) {
                    int k = kc * 32 + gg * 8 + jj;
                    vals[jj] = (av && k < CIN) ? xrow[k] : 0.f;
                }
            }
            union { short8 v; unsigned short u[8]; } hu, lu;
            #pragma unroll
            for (int jj = 0; jj < 8; jj++) bsplit(vals[jj], hu.u[jj], lu.u[jj]);
            a_hi[kc] = hu.v; a_lo[kc] = lu.v;
        }
    }

    float out[HT][4];
    #pragma unroll
    for (int q = 0; q < HT; q++)
        #pragma unroll
        for (int e = 0; e < 4; e++) out[q][e] = 0.f;

    float    mf[MPACK ? 1 : HT][4];      // per-head messages, f32 variant
    unsigned mpk[MPACK ? HT : 1][2];     // per-head messages, bf16x2 variant

    __syncthreads();

    const int boff = gg * 128 + r * 8;       // transposed-chunk read offset (conflict-free)

    // ---- heads ----
    for (int h = 0; h < H; h++) {
        float p[4] = {0.f, 0.f, 0.f, 0.f};
        #pragma unroll
        for (int q = 0; q < HT; q++) {
            const int nt  = h * HT + q;
            const int cur = nt & 1;
            const int ntn = nt + 1;
            const bool doStage = (ntn < NTOT);
            f32x4 sreg[CHPT];
            if (doStage) {                              // issue loads early (hide under MFMA)
                const f32x4* ps = (const f32x4*)pw + (size_t)ntn * NCH;
                #pragma unroll
                for (int i = 0; i < CHPT; i++) { int idx = tid + i * NTHR; if (idx < NCH) sreg[i] = ps[idx]; }
            }
            const int col = nt * 16 + r;
            const float2 pv = *(const float2*)&pl[col * 2];   // (bm, att) via LDS
            short8 bh[KC], bl[KC];
            #pragma unroll
            for (int kc = 0; kc < KC; kc++) {
                bh[kc] = *(const short8*)&bufs[cur][(kc * 2 + 0) * 512 + boff];
                bl[kc] = *(const short8*)&bufs[cur][(kc * 2 + 1) * 512 + boff];
            }
            f32x4 acc0 = {pv.x, pv.x, pv.x, pv.x};      // hi*hi chain (seeded with bias)
            f32x4 acc1 = {0.f, 0.f, 0.f, 0.f};          // hi*lo chain
            f32x4 acc2 = {0.f, 0.f, 0.f, 0.f};          // lo*hi chain
            #pragma unroll
            for (int kc = 0; kc < KC; kc++) {
                acc0 = __builtin_amdgcn_mfma_f32_16x16x32_bf16(a_hi[kc], bh[kc], acc0, 0, 0, 0);
                acc1 = __builtin_amdgcn_mfma_f32_16x16x32_bf16(a_hi[kc], bl[kc], acc1, 0, 0, 0);
                acc2 = __builtin_amdgcn_mfma_f32_16x16x32_bf16(a_lo[kc], bh[kc], acc2, 0, 0, 0);
            }
            float vv[4];
            #pragma unroll
            for (int e = 0; e < 4; e++) {
                float v = acc0[e] + acc1[e] + acc2[e];
                v = v > 0.f ? v : 0.01f * v;        // leaky_relu(0.01)
                vv[e] = v;
                p[e] += v * pv.y;                   // logit partial (col r)
            }
            if constexpr (MPACK) {
                mpk[q][0] = ((unsigned)rne_bf16(vv[1]) << 16) | rne_bf16(vv[0]);
                mpk[q][1] = ((unsigned)rne_bf16(vv[3]) << 16) | rne_bf16(vv[2]);
            } else {
                #pragma unroll
                for (int e = 0; e < 4; e++) mf[q][e] = vv[e];
            }
            if (doStage) {                              // write-late (loads have landed)
                const int nb = ntn & 1;
                #pragma unroll
                for (int i = 0; i < CHPT; i++) { int idx = tid + i * NTHR; if (idx < NCH) *(f32x4*)&bufs[nb][idx * 8] = sreg[i]; }
            }
            __syncthreads();
        }
        // ---- logits: butterfly all-reduce over the 16 lanes of each row ----
        #pragma unroll
        for (int e = 0; e < 4; e++) {
            float v = p[e];
            v += __shfl_xor(v, 1, 64);
            v += __shfl_xor(v, 2, 64);
            v += __shfl_xor(v, 4, 64);
            v += __shfl_xor(v, 8, 64);
            p[e] = v;                                   // alpha[row gg*4+e]
        }
        // ---- softmax over <=2 incoming edges + aggregate into out regs ----
        {
            const int jbase = w * 14;
            float a3u = __shfl_up(p[3], 16, 64);        // alpha of row-1 for e==0
            float a0d = __shfl_down(p[0], 16, 64);      // alpha of row+1 for e==3
            float wpv[4], wnv[4];
            #pragma unroll
            for (int e = 0; e < 4; e++) {
                const int jr = gg * 4 + e;
                const int nl = n0 - 1 + jbase + jr;     // within-graph node idx
                const bool hp = nl >= 1;
                const bool hn = nl < NLEN - 1;
                float ap = (e > 0) ? p[e - 1] : a3u;
                float an = (e < 3) ? p[e + 1] : a0d;
                float apx = hp ? ap : -1e30f;
                float anx = hn ? an : -1e30f;
                float mx = fmaxf(apx, anx);
                float ep = hp ? __expf(ap - mx) : 0.f;
                float en = hn ? __expf(an - mx) : 0.f;
                float inv = 1.f / (ep + en + 1e-16f);
                wpv[e] = ep * inv; wnv[e] = en * inv;
            }
            #pragma unroll
            for (int q = 0; q < HT; q++) {
                float v0, v1, v2, v3;
                if constexpr (MPACK) {
                    v0 = bf16_to_f((unsigned short)(mpk[q][0] & 0xffff));
                    v1 = bf16_to_f((unsigned short)(mpk[q][0] >> 16));
                    v2 = bf16_to_f((unsigned short)(mpk[q][1] & 0xffff));
                    v3 = bf16_to_f((unsigned short)(mpk[q][1] >> 16));
                } else {
                    v0 = mf[q][0]; v1 = mf[q][1]; v2 = mf[q][2]; v3 = mf[q][3];
                }
                float m3u = __shfl_up(v3, 16, 64);      // M[row-1] for e==0
                float m0d = __shfl_down(v0, 16, 64);    // M[row+1] for e==3
                float mvals[4] = {v0, v1, v2, v3};
                #pragma unroll
                for (int e = 0; e < 4; e++) {
                    float mprev = (e > 0) ? mvals[e - 1] : m3u;
                    float mnext = (e < 3) ? mvals[e + 1] : m0d;
                    out[q][e] += wpv[e] * mprev + wnv[e] * mnext;
                }
            }
        }
    }

    // ---- self-loop tiles + finalize + store ----
    #pragma unroll
    for (int q2 = 0; q2 < HT; q2++) {
        const int nt  = MT + q2;
        const int cur = nt & 1;
        const int ntn = nt + 1;
        const bool doStage = (ntn < NTOT);
        f32x4 sreg[CHPT];
        if (doStage) {
            const f32x4* ps = (const f32x4*)pw + (size_t)ntn * NCH;
            #pragma unroll
            for (int i = 0; i < CHPT; i++) { int idx = tid + i * NTHR; if (idx < NCH) sreg[i] = ps[idx]; }
        }
        const int c2  = q2 * 16 + r;
        const float bsv = pl[(HC + c2) * 2];
        short8 bh[KC], bl[KC];
        #pragma unroll
        for (int kc = 0; kc < KC; kc++) {
            bh[kc] = *(const short8*)&bufs[cur][(kc * 2 + 0) * 512 + boff];
            bl[kc] = *(const short8*)&bufs[cur][(kc * 2 + 1) * 512 + boff];
        }
        f32x4 acc0 = {bsv, bsv, bsv, bsv};
        f32x4 acc1 = {0.f, 0.f, 0.f, 0.f};
        f32x4 acc2 = {0.f, 0.f, 0.f, 0.f};
        #pragma unroll
        for (int kc = 0; kc < KC; kc++) {
            acc0 = __builtin_amdgcn_mfma_f32_16x16x32_bf16(a_hi[kc], bh[kc], acc0, 0, 0, 0);
            acc1 = __builtin_amdgcn_mfma_f32_16x16x32_bf16(a_hi[kc], bl[kc], acc1, 0, 0, 0);
            acc2 = __builtin_amdgcn_mfma_f32_16x16x32_bf16(a_lo[kc], bh[kc], acc2, 0, 0, 0);
        }
        const int jbase = w * 14;
        #pragma unroll
        for (int e = 0; e < 4; e++) {
            const int jr = gg * 4 + e;
            const int nl = n0 - 1 + jbase + jr;
            float v = out[q2][e] * invH + (acc0[e] + acc1[e] + acc2[e]);
            v = v > 0.f ? v : __expf(v) - 1.f;          // ELU (layers 1..4)
            if (jr >= 1 && jr <= 14 && nl < NLEN)
                y[(gstart + nl) * COUT + c2] = v;
        }
        if (doStage) {
            const int nb = ntn & 1;
            #pragma unroll
            for (int i = 0; i < CHPT; i++) { int idx = tid + i * NTHR; if (idx < NCH) *(f32x4*)&bufs[nb][idx * 8] = sreg[i]; }
        }
        __syncthreads();
    }
}

// Layer 5 + head at the last node per graph (single incoming edge -> softmax weight 1).
__global__ void final_head(const float* __restrict__ x4,   // [NUMV][64]
                           const float* __restrict__ Wm,   // [64][32]
                           const float* __restrict__ bm,
                           const float* __restrict__ Ws,   // [64][32]
                           const float* __restrict__ bs,
                           const float* __restrict__ Wc,   // [32][1]
                           const float* __restrict__ bc,
                           float* __restrict__ out)        // [32] ++ [32*32]
{
    int g = blockIdx.x;
    int c = threadIdx.x;
    const float* xu = &x4[((long)g * NLEN + NLEN - 2) * 64];
    const float* xv = xu + 64;
    float o = 0.f;
    if (c < 32) {
        float m = bm[c];
        float s = bs[c];
        for (int k = 0; k < 64; k++) {
            m = fmaf(xu[k], Wm[k * 32 + c], m);
            s = fmaf(xv[k], Ws[k * 32 + c], s);
        }
        m = m > 0.f ? m : 0.01f * m;
        o = m + s;
        out[32 + g * 32 + c] = o;
    }
    float tsum = (c < 32) ? o * Wc[c] : 0.f;
    #pragma unroll
    for (int sft = 16; sft > 0; sft >>= 1)
        tsum += __shfl_xor(tsum, sft, 64);
    if (c == 0) out[g] = tsum + bc[0];
}

extern "C" void kernel_launch(void* const* d_in, const int* in_sizes, int n_in,
                              void* d_out, int out_size, void* d_ws, size_t ws_size,
                              hipStream_t stream)
{
    const float* nodes = (const float*)d_in[0];
    auto L = [&](int l, int k) { return (const float*)d_in[1 + (l - 1) * 5 + k]; };

    float* xb0 = (float*)d_ws;                       // [NUMV][128] f32
    float* xb1 = xb0 + (size_t)NUMV * 128;
    unsigned short* p1 = (unsigned short*)(xb1 + (size_t)NUMV * 128);
    unsigned short* p2 = p1 + 72 * 1024;             // L1: NT=72, KC=1
    unsigned short* p3 = p2 + 72 * 4096;             // L2: NT=72, KC=4
    unsigned short* p4 = p3 + 68 * 4096;             // L3: NT=68, KC=4
                                                     // L4: NT=68, KC=2

    pack_all<<<dim3(512), dim3(256), 0, stream>>>(
        L(1,0), L(1,2), L(2,0), L(2,2), L(3,0), L(3,2), L(4,0), L(4,2), p1, p2, p3, p4);

    constexpr int TPG = (NLEN + 27) / 28;            // 37
    dim3 grid(BATCH * TPG);                          // 1184 blocks
    dim3 blk(128);

    conv_reg<1,   128, 8,  false><<<grid, blk, 0, stream>>>(nodes, p1, L(1,1), L(1,3), L(1,4), xb0);
    conv_reg<128, 128, 8,  true ><<<grid, blk, 0, stream>>>(xb0,   p2, L(2,1), L(2,3), L(2,4), xb1);
    conv_reg<128, 64,  16, false><<<grid, blk, 0, stream>>>(xb1,   p3, L(3,1), L(3,3), L(3,4), xb0);
    conv_reg<64,  64,  16, false><<<grid, blk, 0, stream>>>(xb0,   p4, L(4,1), L(4,3), L(4,4), xb1);

    final_head<<<dim3(BATCH), dim3(64), 0, stream>>>(
        xb1, L(5,0), L(5,1), L(5,2), L(5,3),
        (const float*)d_in[26], (const float*)d_in[27], (float*)d_out);
}

// Round 7
// 389.145 us; speedup vs baseline: 1.6269x; 1.6269x over previous
//
#include <hip/hip_runtime.h>

#define BATCH 32
#define NLEN  1024
#define NUMV  (BATCH * NLEN)

typedef __attribute__((ext_vector_type(8))) short short8;
typedef __attribute__((ext_vector_type(4))) float f32x4;

__device__ inline unsigned short rne_bf16(float x) {
    union { float f; unsigned u; } a; a.f = x;
    return (unsigned short)((a.u + 0x7FFFu + ((a.u >> 16) & 1u)) >> 16);
}
// fp32 -> bf16 hi + bf16 lo (both RNE): x ~= hi + lo, rel err ~2^-17
__device__ inline void bsplit(float x, unsigned short& h, unsigned short& l) {
    union { float f; unsigned u; } a; a.f = x;
    unsigned hb = (a.u + 0x7FFFu + ((a.u >> 16) & 1u)) & 0xFFFF0000u;
    h = (unsigned short)(hb >> 16);
    union { unsigned u; float f; } hf; hf.u = hb;
    l = rne_bf16(x - hf.f);
}
__device__ inline float bf16_to_f(unsigned short v) {
    union { unsigned u; float f; } a; a.u = ((unsigned)v) << 16; return a.f;
}

template<int N> __device__ __forceinline__ void wait_vmcnt() {
    if constexpr (N == 0)      asm volatile("s_waitcnt vmcnt(0)" ::: "memory");
    else if constexpr (N == 1) asm volatile("s_waitcnt vmcnt(1)" ::: "memory");
    else if constexpr (N == 2) asm volatile("s_waitcnt vmcnt(2)" ::: "memory");
    else if constexpr (N == 4) asm volatile("s_waitcnt vmcnt(4)" ::: "memory");
    else static_assert(N == 0 || N == 1 || N == 2 || N == 4, "");
}

// Packed layout per layer (bank-conflict-free transposed chunks):
//   f = ((nt*KC + kc)*2 + hl)*512 + g*128 + c*8 + j
//   -> W[k = kc*32+g*8+j][col = nt*16+c], W = [Wm | Ws], zero-pad k >= CIN.
// hl: 0 = hi bf16, 1 = lo bf16. One B tile contiguous: KC*2KB. LDS image = exact
// linear copy -> global_load_lds (wave-uniform dest + lane*16) works directly.
template<int CIN, int COUT, int H>
__device__ void pack_layer(const float* __restrict__ Wm, const float* __restrict__ Ws,
                           unsigned short* __restrict__ out, int t0, int nthr)
{
    constexpr int HC = H * COUT;
    constexpr int KC = ((CIN + 31) & ~31) / 32;
    constexpr int NT = (HC + COUT) / 16;
    const int total = NT * KC * 1024;
    for (int f = t0; f < total; f += nthr) {
        int j  = f & 7;
        int c  = (f >> 3) & 15;
        int g  = (f >> 7) & 3;
        int hl = (f >> 9) & 1;
        int r2 = f >> 10;
        int kc = r2 % KC, nt = r2 / KC;
        int k = kc * 32 + g * 8 + j, col = nt * 16 + c;
        float v = 0.f;
        if (k < CIN) v = (col < HC) ? Wm[k * HC + col] : Ws[k * COUT + (col - HC)];
        unsigned short h, l; bsplit(v, h, l);
        out[f] = hl ? l : h;
    }
}

__global__ void pack_all(const float* Wm1, const float* Ws1, const float* Wm2, const float* Ws2,
                         const float* Wm3, const float* Ws3, const float* Wm4, const float* Ws4,
                         unsigned short* p1, unsigned short* p2, unsigned short* p3, unsigned short* p4)
{
    int t = blockIdx.x * 256 + threadIdx.x;
    int n = gridDim.x * 256;
    pack_layer<1, 128, 8>(Wm1, Ws1, p1, t, n);
    pack_layer<128, 128, 8>(Wm2, Ws2, p2, t, n);
    pack_layer<128, 64, 16>(Wm3, Ws3, p3, t, n);
    pack_layer<64, 64, 16>(Wm4, Ws4, p4, t, n);
}

// Fused GeneralConv layer. Block = 4 waves x 16 rows (14 useful), 56 rows/block,
// grid = 32*19 = 608 blocks, all co-resident (41KB LDS -> 3 blocks/CU cap).
// B staged via global_load_lds into double-buffered 2-tile halves; counted
// vmcnt(KC) at half entry (never 0 in steady state); raw s_barrier + sched pins.
template<int CIN, int COUT, int H, bool MPACK>
__global__ __launch_bounds__(256, 3)
void conv_reg(const float* __restrict__ x, const unsigned short* __restrict__ pw,
              const float* __restrict__ bm, const float* __restrict__ bs,
              const float* __restrict__ att, float* __restrict__ y)
{
    constexpr int HC = H * COUT;
    static_assert(HC == 1024, "");
    constexpr int KC   = ((CIN + 31) & ~31) / 32;
    constexpr int HT   = COUT / 16;          // tiles per head == self tiles
    constexpr int MT   = HC / 16;            // 64 message tiles
    constexpr int CPH  = 2 * KC * 128;       // 16B chunks per half (2 tiles)
    constexpr int ROWSB = 56;
    constexpr int TPG  = (NLEN + ROWSB - 1) / ROWSB;  // 19
    constexpr int PL   = HC + COUT;
    constexpr float invH = 1.0f / H;

    const int tid  = threadIdx.x;
    const int lane = tid & 63;
    const int w    = tid >> 6;                // wave 0..3 (uniform per wave)
    const int r    = lane & 15;               // A row in set / B col / C col
    const int gg   = lane >> 4;               // k-group; C row = gg*4+e
    const int g    = blockIdx.x / TPG;
    const int n0   = (blockIdx.x % TPG) * ROWSB;
    const size_t gstart = (size_t)g * NLEN;

    __shared__ alignas(16) unsigned short bufs[2][2 * KC * 1024];  // 2 halves x 2 tiles
    __shared__ alignas(8) float pl[PL * 2];   // (bm,att) msg cols; (bs,-) self cols

    // ---- prologue: params -> LDS ----
    for (int i = tid; i < PL; i += 256) {
        float a, b;
        if (i < HC) { a = bm[i]; b = att[i]; }
        else        { a = bs[i - HC]; b = 0.f; }
        pl[2 * i] = a; pl[2 * i + 1] = b;
    }

    // ---- A fragments (one row-set, built once from global) ----
    short8 a_hi[KC], a_lo[KC];
    {
        const int na = n0 - 1 + w * 14 + r;          // within-graph node of A row
        const bool av = (na >= 0) && (na < NLEN);
        const float* xrow = x + (gstart + (size_t)(av ? na : 0)) * CIN;
        #pragma unroll
        for (int kc = 0; kc < KC; kc++) {
            float vals[8];
            if constexpr (CIN % 32 == 0) {
                if (av) {
                    f32x4 v0 = *(const f32x4*)(xrow + kc * 32 + gg * 8);
                    f32x4 v1 = *(const f32x4*)(xrow + kc * 32 + gg * 8 + 4);
                    vals[0]=v0[0]; vals[1]=v0[1]; vals[2]=v0[2]; vals[3]=v0[3];
                    vals[4]=v1[0]; vals[5]=v1[1]; vals[6]=v1[2]; vals[7]=v1[3];
                } else {
                    #pragma unroll
                    for (int jj = 0; jj < 8; jj++) vals[jj] = 0.f;
                }
            } else {
                #pragma unroll
                for (int jj = 0; jj < 8; jj++) {
                    int k = kc * 32 + gg * 8 + jj;
                    vals[jj] = (av && k < CIN) ? xrow[k] : 0.f;
                }
            }
            union { short8 v; unsigned short u[8]; } hu, lu;
            #pragma unroll
            for (int jj = 0; jj < 8; jj++) bsplit(vals[jj], hu.u[jj], lu.u[jj]);
            a_hi[kc] = hu.v; a_lo[kc] = lu.v;
        }
    }

    // fire-and-forget half staging: wave w loads chunks [(w*KC+i)*64, +64) of the half
    auto issue_half = [&](int hh, int par) {
        const size_t cbase = (size_t)hh * CPH;
        #pragma unroll
        for (int i = 0; i < KC; i++) {
            const int chunk0 = (w * KC + i) * 64;
            const unsigned short* gsrc = pw + (cbase + chunk0 + lane) * 8;
            unsigned short* ldst = &bufs[par][chunk0 * 8];
            __builtin_amdgcn_global_load_lds(
                (const __attribute__((address_space(1))) void*)gsrc,
                (__attribute__((address_space(3))) void*)ldst,
                16, 0, 0);
        }
    };

    float out[HT][4];
    #pragma unroll
    for (int q = 0; q < HT; q++)
        #pragma unroll
        for (int e = 0; e < 4; e++) out[q][e] = 0.f;

    float    mf[MPACK ? 1 : HT][4];      // per-head messages, f32 variant
    unsigned mpk[MPACK ? HT : 1][2];     // per-head messages, bf16x2 variant

    issue_half(0, 0);
    issue_half(1, 1);
    asm volatile("s_waitcnt lgkmcnt(0)" ::: "memory");   // pl ds_writes drained

    const int boff = gg * 128 + r * 8;   // transposed-chunk read offset (conflict-free)

    // ---- message tiles, per head ----
    for (int h = 0; h < H; h++) {
        float p[4] = {0.f, 0.f, 0.f, 0.f};
        #pragma unroll
        for (int hq = 0; hq < HT / 2; hq++) {
            const int par = hq & 1;              // == hh&1 (h*(HT/2) even stride)
            const int hh  = h * (HT / 2) + hq;
            wait_vmcnt<KC>();                    // half hh landed (hh+1 in flight)
            __builtin_amdgcn_s_barrier();
            __builtin_amdgcn_sched_barrier(0);
            #pragma unroll
            for (int t2 = 0; t2 < 2; t2++) {
                const int q   = hq * 2 + t2;     // compile-time (static reg index)
                const int nt  = h * HT + q;
                const int col = nt * 16 + r;
                const float2 pv = *(const float2*)&pl[col * 2];
                short8 bh[KC], bl[KC];
                #pragma unroll
                for (int kc = 0; kc < KC; kc++) {
                    bh[kc] = *(const short8*)&bufs[par][t2 * KC * 1024 + (kc * 2 + 0) * 512 + boff];
                    bl[kc] = *(const short8*)&bufs[par][t2 * KC * 1024 + (kc * 2 + 1) * 512 + boff];
                }
                f32x4 acc0 = {pv.x, pv.x, pv.x, pv.x};
                f32x4 acc1 = {0.f, 0.f, 0.f, 0.f};
                f32x4 acc2 = {0.f, 0.f, 0.f, 0.f};
                #pragma unroll
                for (int kc = 0; kc < KC; kc++) {
                    acc0 = __builtin_amdgcn_mfma_f32_16x16x32_bf16(a_hi[kc], bh[kc], acc0, 0, 0, 0);
                    acc1 = __builtin_amdgcn_mfma_f32_16x16x32_bf16(a_hi[kc], bl[kc], acc1, 0, 0, 0);
                    acc2 = __builtin_amdgcn_mfma_f32_16x16x32_bf16(a_lo[kc], bh[kc], acc2, 0, 0, 0);
                }
                float vv[4];
                #pragma unroll
                for (int e = 0; e < 4; e++) {
                    float v = acc0[e] + acc1[e] + acc2[e];
                    v = v > 0.f ? v : 0.01f * v;        // leaky_relu(0.01)
                    vv[e] = v;
                    p[e] += v * pv.y;                   // logit partial (col r)
                }
                if constexpr (MPACK) {
                    mpk[q][0] = ((unsigned)rne_bf16(vv[1]) << 16) | rne_bf16(vv[0]);
                    mpk[q][1] = ((unsigned)rne_bf16(vv[3]) << 16) | rne_bf16(vv[2]);
                } else {
                    #pragma unroll
                    for (int e = 0; e < 4; e++) mf[q][e] = vv[e];
                }
            }
            __builtin_amdgcn_sched_barrier(0);
            __builtin_amdgcn_s_barrier();        // all waves done reading bufs[par]
            __builtin_amdgcn_sched_barrier(0);
            issue_half(hh + 2, par);             // always < NH in msg loop
        }
        // ---- logits: butterfly all-reduce over 16 lanes of each row ----
        #pragma unroll
        for (int e = 0; e < 4; e++) {
            float v = p[e];
            v += __shfl_xor(v, 1, 64);
            v += __shfl_xor(v, 2, 64);
            v += __shfl_xor(v, 4, 64);
            v += __shfl_xor(v, 8, 64);
            p[e] = v;                                   // alpha[row gg*4+e]
        }
        // ---- softmax over <=2 incoming edges + aggregate into out regs ----
        {
            const int jbase = w * 14;
            float a3u = __shfl_up(p[3], 16, 64);        // alpha row-1 for e==0
            float a0d = __shfl_down(p[0], 16, 64);      // alpha row+1 for e==3
            float wpv[4], wnv[4];
            #pragma unroll
            for (int e = 0; e < 4; e++) {
                const int jr = gg * 4 + e;
                const int nl = n0 - 1 + jbase + jr;
                const bool hp = nl >= 1;
                const bool hn = nl < NLEN - 1;
                float ap = (e > 0) ? p[e - 1] : a3u;
                float an = (e < 3) ? p[e + 1] : a0d;
                float apx = hp ? ap : -1e30f;
                float anx = hn ? an : -1e30f;
                float mx = fmaxf(apx, anx);
                float ep = hp ? __expf(ap - mx) : 0.f;
                float en = hn ? __expf(an - mx) : 0.f;
                float inv = 1.f / (ep + en + 1e-16f);
                wpv[e] = ep * inv; wnv[e] = en * inv;
            }
            #pragma unroll
            for (int q = 0; q < HT; q++) {
                float v0, v1, v2, v3;
                if constexpr (MPACK) {
                    v0 = bf16_to_f((unsigned short)(mpk[q][0] & 0xffff));
                    v1 = bf16_to_f((unsigned short)(mpk[q][0] >> 16));
                    v2 = bf16_to_f((unsigned short)(mpk[q][1] & 0xffff));
                    v3 = bf16_to_f((unsigned short)(mpk[q][1] >> 16));
                } else {
                    v0 = mf[q][0]; v1 = mf[q][1]; v2 = mf[q][2]; v3 = mf[q][3];
                }
                float m3u = __shfl_up(v3, 16, 64);
                float m0d = __shfl_down(v0, 16, 64);
                float mvals[4] = {v0, v1, v2, v3};
                #pragma unroll
                for (int e = 0; e < 4; e++) {
                    float mprev = (e > 0) ? mvals[e - 1] : m3u;
                    float mnext = (e < 3) ? mvals[e + 1] : m0d;
                    out[q][e] += wpv[e] * mprev + wnv[e] * mnext;
                }
            }
        }
    }

    // ---- self-loop halves + finalize + store ----
    #pragma unroll
    for (int q2h = 0; q2h < HT / 2; q2h++) {
        const int hh  = MT / 2 + q2h;
        const int par = q2h & 1;                 // MT/2 even
        if (q2h < HT / 2 - 1) wait_vmcnt<KC>(); else wait_vmcnt<0>();
        __builtin_amdgcn_s_barrier();
        __builtin_amdgcn_sched_barrier(0);
        #pragma unroll
        for (int t2 = 0; t2 < 2; t2++) {
            const int q2 = q2h * 2 + t2;
            const int c2 = q2 * 16 + r;
            const float bsv = pl[(HC + c2) * 2];
            short8 bh[KC], bl[KC];
            #pragma unroll
            for (int kc = 0; kc < KC; kc++) {
                bh[kc] = *(const short8*)&bufs[par][t2 * KC * 1024 + (kc * 2 + 0) * 512 + boff];
                bl[kc] = *(const short8*)&bufs[par][t2 * KC * 1024 + (kc * 2 + 1) * 512 + boff];
            }
            f32x4 acc0 = {bsv, bsv, bsv, bsv};
            f32x4 acc1 = {0.f, 0.f, 0.f, 0.f};
            f32x4 acc2 = {0.f, 0.f, 0.f, 0.f};
            #pragma unroll
            for (int kc = 0; kc < KC; kc++) {
                acc0 = __builtin_amdgcn_mfma_f32_16x16x32_bf16(a_hi[kc], bh[kc], acc0, 0, 0, 0);
                acc1 = __builtin_amdgcn_mfma_f32_16x16x32_bf16(a_hi[kc], bl[kc], acc1, 0, 0, 0);
                acc2 = __builtin_amdgcn_mfma_f32_16x16x32_bf16(a_lo[kc], bh[kc], acc2, 0, 0, 0);
            }
            const int jbase = w * 14;
            #pragma unroll
            for (int e = 0; e < 4; e++) {
                const int jr = gg * 4 + e;
                const int nl = n0 - 1 + jbase + jr;
                float v = out[q2][e] * invH + (acc0[e] + acc1[e] + acc2[e]);
                v = v > 0.f ? v : __expf(v) - 1.f;      // ELU (layers 1..4)
                if (jr >= 1 && jr <= 14 && nl < NLEN)
                    y[(gstart + nl) * COUT + c2] = v;
            }
        }
        __builtin_amdgcn_sched_barrier(0);
        __builtin_amdgcn_s_barrier();
        __builtin_amdgcn_sched_barrier(0);
        if (q2h + 2 < HT / 2) issue_half(hh + 2, par);
    }
}

// Layer 5 + head at the last node per graph (single incoming edge -> softmax weight 1).
__global__ void final_head(const float* __restrict__ x4,   // [NUMV][64]
                           const float* __restrict__ Wm,   // [64][32]
                           const float* __restrict__ bm,
                           const float* __restrict__ Ws,   // [64][32]
                           const float* __restrict__ bs,
                           const float* __restrict__ Wc,   // [32][1]
                           const float* __restrict__ bc,
                           float* __restrict__ out)        // [32] ++ [32*32]
{
    int g = blockIdx.x;
    int c = threadIdx.x;
    const float* xu = &x4[((long)g * NLEN + NLEN - 2) * 64];
    const float* xv = xu + 64;
    float o = 0.f;
    if (c < 32) {
        float m = bm[c];
        float s = bs[c];
        for (int k = 0; k < 64; k++) {
            m = fmaf(xu[k], Wm[k * 32 + c], m);
            s = fmaf(xv[k], Ws[k * 32 + c], s);
        }
        m = m > 0.f ? m : 0.01f * m;
        o = m + s;
        out[32 + g * 32 + c] = o;
    }
    float tsum = (c < 32) ? o * Wc[c] : 0.f;
    #pragma unroll
    for (int sft = 16; sft > 0; sft >>= 1)
        tsum += __shfl_xor(tsum, sft, 64);
    if (c == 0) out[g] = tsum + bc[0];
}

extern "C" void kernel_launch(void* const* d_in, const int* in_sizes, int n_in,
                              void* d_out, int out_size, void* d_ws, size_t ws_size,
                              hipStream_t stream)
{
    const float* nodes = (const float*)d_in[0];
    auto L = [&](int l, int k) { return (const float*)d_in[1 + (l - 1) * 5 + k]; };

    float* xb0 = (float*)d_ws;                       // [NUMV][128] f32
    float* xb1 = xb0 + (size_t)NUMV * 128;
    unsigned short* p1 = (unsigned short*)(xb1 + (size_t)NUMV * 128);
    unsigned short* p2 = p1 + 72 * 1024;             // L1: NT=72, KC=1
    unsigned short* p3 = p2 + 72 * 4096;             // L2: NT=72, KC=4
    unsigned short* p4 = p3 + 68 * 4096;             // L3: NT=68, KC=4
                                                     // L4: NT=68, KC=2

    pack_all<<<dim3(512), dim3(256), 0, stream>>>(
        L(1,0), L(1,2), L(2,0), L(2,2), L(3,0), L(3,2), L(4,0), L(4,2), p1, p2, p3, p4);

    constexpr int TPG = (NLEN + 55) / 56;            // 19
    dim3 grid(BATCH * TPG);                          // 608 blocks
    dim3 blk(256);

    conv_reg<1,   128, 8,  false><<<grid, blk, 0, stream>>>(nodes, p1, L(1,1), L(1,3), L(1,4), xb0);
    conv_reg<128, 128, 8,  true ><<<grid, blk, 0, stream>>>(xb0,   p2, L(2,1), L(2,3), L(2,4), xb1);
    conv_reg<128, 64,  16, false><<<grid, blk, 0, stream>>>(xb1,   p3, L(3,1), L(3,3), L(3,4), xb0);
    conv_reg<64,  64,  16, false><<<grid, blk, 0, stream>>>(xb0,   p4, L(4,1), L(4,3), L(4,4), xb1);

    final_head<<<dim3(BATCH), dim3(64), 0, stream>>>(
        xb1, L(5,0), L(5,1), L(5,2), L(5,3),
        (const float*)d_in[26], (const float*)d_in[27], (float*)d_out);
}